// Round 1
// baseline (77.582 us; speedup 1.0000x reference)
//
#include <hip/hip_runtime.h>
#include <math.h>

constexpr int NPTS = 1024;

__global__ __launch_bounds__(256) void kabsch_kernel(
    const float* __restrict__ src, const float* __restrict__ tgt,
    float* __restrict__ out, int nbatch)
{
    const int b = blockIdx.x;
    const int tid = threadIdx.x;
    const size_t base = (size_t)b * (NPTS * 3);
    const float* sp = src + base + tid * 12;
    const float* tp = tgt + base + tid * 12;

    // 4 points = 12 contiguous floats per thread, 16B-aligned float4 loads
    float4 sA = *(const float4*)(sp + 0);
    float4 sB = *(const float4*)(sp + 4);
    float4 sC = *(const float4*)(sp + 8);
    float4 tA = *(const float4*)(tp + 0);
    float4 tB = *(const float4*)(tp + 4);
    float4 tC = *(const float4*)(tp + 8);

    float sx[4] = {sA.x, sA.w, sB.z, sC.y};
    float sy[4] = {sA.y, sB.x, sB.w, sC.z};
    float sz[4] = {sA.z, sB.y, sC.x, sC.w};
    float tx[4] = {tA.x, tA.w, tB.z, tC.y};
    float ty[4] = {tA.y, tB.x, tB.w, tC.z};
    float tz[4] = {tA.z, tB.y, tC.x, tC.w};

    // 15 partial sums: sum(src)[3], sum(tgt)[3], M[i][j]=sum(src_i*tgt_j)[9]
    float acc[15];
#pragma unroll
    for (int i = 0; i < 15; ++i) acc[i] = 0.f;
#pragma unroll
    for (int j = 0; j < 4; ++j) {
        acc[0] += sx[j]; acc[1] += sy[j]; acc[2] += sz[j];
        acc[3] += tx[j]; acc[4] += ty[j]; acc[5] += tz[j];
        acc[6]  += sx[j] * tx[j]; acc[7]  += sx[j] * ty[j]; acc[8]  += sx[j] * tz[j];
        acc[9]  += sy[j] * tx[j]; acc[10] += sy[j] * ty[j]; acc[11] += sy[j] * tz[j];
        acc[12] += sz[j] * tx[j]; acc[13] += sz[j] * ty[j]; acc[14] += sz[j] * tz[j];
    }

    // wave (64-lane) butterfly reduce
#pragma unroll
    for (int off = 32; off >= 1; off >>= 1) {
#pragma unroll
        for (int i = 0; i < 15; ++i)
            acc[i] += __shfl_down(acc[i], off, 64);
    }

    __shared__ float part[4][15];
    const int wave = tid >> 6;
    const int lane = tid & 63;
    if (lane == 0) {
#pragma unroll
        for (int i = 0; i < 15; ++i) part[wave][i] = acc[i];
    }
    __syncthreads();
    if (tid != 0) return;

    float r[15];
#pragma unroll
    for (int i = 0; i < 15; ++i)
        r[i] = part[0][i] + part[1][i] + part[2][i] + part[3][i];

    const float invN = 1.0f / (float)NPTS;
    float mus[3] = {r[0] * invN, r[1] * invN, r[2] * invN};
    float mut[3] = {r[3] * invN, r[4] * invN, r[5] * invN};

    // H[i][j] = M[i][j] - N * mus_i * mut_j
    float H[3][3];
#pragma unroll
    for (int i = 0; i < 3; ++i)
#pragma unroll
        for (int j = 0; j < 3; ++j)
            H[i][j] = r[6 + i * 3 + j] - (float)NPTS * mus[i] * mut[j];

    // A = H^T H (symmetric, PSD)
    float A[3][3];
#pragma unroll
    for (int i = 0; i < 3; ++i)
#pragma unroll
        for (int j = 0; j < 3; ++j)
            A[i][j] = H[0][i] * H[0][j] + H[1][i] * H[1][j] + H[2][i] * H[2][j];

    // cyclic Jacobi eigensolver -> A diag = eigenvalues, V columns = eigenvectors
    float V[3][3] = {{1.f, 0.f, 0.f}, {0.f, 1.f, 0.f}, {0.f, 0.f, 1.f}};
    auto rot = [&](int p, int q) {
        float apq = A[p][q];
        if (fabsf(apq) < 1e-30f) return;
        float theta = (A[q][q] - A[p][p]) / (2.0f * apq);
        float t = copysignf(1.0f, theta) / (fabsf(theta) + sqrtf(theta * theta + 1.0f));
        float c = 1.0f / sqrtf(t * t + 1.0f);
        float s = t * c;
#pragma unroll
        for (int k = 0; k < 3; ++k) {      // A <- A J
            float akp = A[k][p], akq = A[k][q];
            A[k][p] = c * akp - s * akq;
            A[k][q] = s * akp + c * akq;
        }
#pragma unroll
        for (int k = 0; k < 3; ++k) {      // A <- J^T A
            float apk = A[p][k], aqk = A[q][k];
            A[p][k] = c * apk - s * aqk;
            A[q][k] = s * apk + c * aqk;
        }
#pragma unroll
        for (int k = 0; k < 3; ++k) {      // V <- V J
            float vkp = V[k][p], vkq = V[k][q];
            V[k][p] = c * vkp - s * vkq;
            V[k][q] = s * vkp + c * vkq;
        }
    };
    for (int sweep = 0; sweep < 12; ++sweep) {
        rot(0, 1);
        rot(0, 2);
        rot(1, 2);
    }

    // sort eigenpairs descending
    float lam[3] = {A[0][0], A[1][1], A[2][2]};
    int idx[3] = {0, 1, 2};
#pragma unroll
    for (int i = 0; i < 2; ++i)
#pragma unroll
        for (int j = i + 1; j < 3; ++j)
            if (lam[idx[j]] > lam[idx[i]]) { int tmp = idx[i]; idx[i] = idx[j]; idx[j] = tmp; }

    float v1[3], v2[3], v3[3];
#pragma unroll
    for (int i = 0; i < 3; ++i) {
        v1[i] = V[i][idx[0]];
        v2[i] = V[i][idx[1]];
        v3[i] = V[i][idx[2]];
    }

    // left singular vectors: u1 = norm(H v1); u2 = GS(H v2); u3 = u1 x u2
    float u1[3], u2[3], u3[3], hv[3];
    hv[0] = H[0][0]*v1[0] + H[0][1]*v1[1] + H[0][2]*v1[2];
    hv[1] = H[1][0]*v1[0] + H[1][1]*v1[1] + H[1][2]*v1[2];
    hv[2] = H[2][0]*v1[0] + H[2][1]*v1[1] + H[2][2]*v1[2];
    {
        float n = 1.0f / sqrtf(hv[0]*hv[0] + hv[1]*hv[1] + hv[2]*hv[2]);
        u1[0] = hv[0] * n; u1[1] = hv[1] * n; u1[2] = hv[2] * n;
    }
    hv[0] = H[0][0]*v2[0] + H[0][1]*v2[1] + H[0][2]*v2[2];
    hv[1] = H[1][0]*v2[0] + H[1][1]*v2[1] + H[1][2]*v2[2];
    hv[2] = H[2][0]*v2[0] + H[2][1]*v2[1] + H[2][2]*v2[2];
    {
        float d = u1[0]*hv[0] + u1[1]*hv[1] + u1[2]*hv[2];
        hv[0] -= d * u1[0]; hv[1] -= d * u1[1]; hv[2] -= d * u1[2];
        float n = 1.0f / sqrtf(hv[0]*hv[0] + hv[1]*hv[1] + hv[2]*hv[2]);
        u2[0] = hv[0] * n; u2[1] = hv[1] * n; u2[2] = hv[2] * n;
    }
    u3[0] = u1[1]*u2[2] - u1[2]*u2[1];
    u3[1] = u1[2]*u2[0] - u1[0]*u2[2];
    u3[2] = u1[0]*u2[1] - u1[1]*u2[0];

    // det(V_sorted) = (v1 x v2) . v3  (= +-1); with det(U)=+1 this is the
    // reflection coefficient: R = v1 u1^T + v2 u2^T + detV * v3 u3^T
    float cx = v1[1]*v2[2] - v1[2]*v2[1];
    float cy = v1[2]*v2[0] - v1[0]*v2[2];
    float cz = v1[0]*v2[1] - v1[1]*v2[0];
    float detV = cx * v3[0] + cy * v3[1] + cz * v3[2];
    float d3 = (detV < 0.f) ? -1.f : 1.f;

    float R[3][3];
#pragma unroll
    for (int i = 0; i < 3; ++i)
#pragma unroll
        for (int j = 0; j < 3; ++j)
            R[i][j] = v1[i]*u1[j] + v2[i]*u2[j] + d3 * v3[i]*u3[j];

    float tvec[3];
#pragma unroll
    for (int i = 0; i < 3; ++i)
        tvec[i] = mut[i] - (R[i][0]*mus[0] + R[i][1]*mus[1] + R[i][2]*mus[2]);

    float* Rout = out + (size_t)b * 9;
#pragma unroll
    for (int i = 0; i < 3; ++i)
#pragma unroll
        for (int j = 0; j < 3; ++j)
            Rout[i * 3 + j] = R[i][j];
    float* tout = out + (size_t)nbatch * 9 + (size_t)b * 3;
#pragma unroll
    for (int i = 0; i < 3; ++i) tout[i] = tvec[i];
}

extern "C" void kernel_launch(void* const* d_in, const int* in_sizes, int n_in,
                              void* d_out, int out_size, void* d_ws, size_t ws_size,
                              hipStream_t stream) {
    const float* src = (const float*)d_in[0];
    const float* tgt = (const float*)d_in[1];
    float* out = (float*)d_out;
    const int nbatch = in_sizes[0] / (NPTS * 3);
    kabsch_kernel<<<nbatch, 256, 0, stream>>>(src, tgt, out, nbatch);
}

// Round 2
// 64.851 us; speedup vs baseline: 1.1963x; 1.1963x over previous
//
#include <hip/hip_runtime.h>
#include <math.h>

constexpr int NPTS = 1024;
constexpr int WAVES_PER_BLOCK = 4;

__global__ __launch_bounds__(256, 4) void kabsch_kernel(
    const float* __restrict__ src, const float* __restrict__ tgt,
    float* __restrict__ out, int nbatch)
{
    const int wave = threadIdx.x >> 6;
    const int lane = threadIdx.x & 63;
    const int b = blockIdx.x * WAVES_PER_BLOCK + wave;
    if (b >= nbatch) return;

    const size_t base = (size_t)b * (NPTS * 3);

    // 15 partial sums: sum(src)[3], sum(tgt)[3], M[i][j]=sum(src_i*tgt_j)[9]
    float acc[15];
#pragma unroll
    for (int i = 0; i < 15; ++i) acc[i] = 0.f;

    // Each lane: 4 groups of 4 points (12 contiguous floats = 3 float4s).
    // Group g = j*64 + lane; wave covers all 1024 points of batch b.
#pragma unroll
    for (int j = 0; j < 4; ++j) {
        const int g = j * 64 + lane;
        const float* sp = src + base + g * 12;
        const float* tp = tgt + base + g * 12;
        float4 sA = *(const float4*)(sp + 0);
        float4 sB = *(const float4*)(sp + 4);
        float4 sC = *(const float4*)(sp + 8);
        float4 tA = *(const float4*)(tp + 0);
        float4 tB = *(const float4*)(tp + 4);
        float4 tC = *(const float4*)(tp + 8);

        float sx[4] = {sA.x, sA.w, sB.z, sC.y};
        float sy[4] = {sA.y, sB.x, sB.w, sC.z};
        float sz[4] = {sA.z, sB.y, sC.x, sC.w};
        float tx[4] = {tA.x, tA.w, tB.z, tC.y};
        float ty[4] = {tA.y, tB.x, tB.w, tC.z};
        float tz[4] = {tA.z, tB.y, tC.x, tC.w};

#pragma unroll
        for (int k = 0; k < 4; ++k) {
            acc[0] += sx[k]; acc[1] += sy[k]; acc[2] += sz[k];
            acc[3] += tx[k]; acc[4] += ty[k]; acc[5] += tz[k];
            acc[6]  += sx[k] * tx[k]; acc[7]  += sx[k] * ty[k]; acc[8]  += sx[k] * tz[k];
            acc[9]  += sy[k] * tx[k]; acc[10] += sy[k] * ty[k]; acc[11] += sy[k] * tz[k];
            acc[12] += sz[k] * tx[k]; acc[13] += sz[k] * ty[k]; acc[14] += sz[k] * tz[k];
        }
    }

    // wave-level butterfly reduce (result valid on lane 0)
#pragma unroll
    for (int off = 32; off >= 1; off >>= 1) {
#pragma unroll
        for (int i = 0; i < 15; ++i)
            acc[i] += __shfl_down(acc[i], off, 64);
    }

    if (lane != 0) return;

    const float invN = 1.0f / (float)NPTS;
    float mus[3] = {acc[0] * invN, acc[1] * invN, acc[2] * invN};
    float mut[3] = {acc[3] * invN, acc[4] * invN, acc[5] * invN};

    // H[i][j] = M[i][j] - N * mus_i * mut_j
    float H[3][3];
#pragma unroll
    for (int i = 0; i < 3; ++i)
#pragma unroll
        for (int j = 0; j < 3; ++j)
            H[i][j] = acc[6 + i * 3 + j] - (float)NPTS * mus[i] * mut[j];

    // A = H^T H (symmetric PSD)
    float A[3][3];
#pragma unroll
    for (int i = 0; i < 3; ++i)
#pragma unroll
        for (int j = 0; j < 3; ++j)
            A[i][j] = H[0][i] * H[0][j] + H[1][i] * H[1][j] + H[2][i] * H[2][j];

    // cyclic Jacobi eigensolver: A -> diag(eigs), V columns = eigenvectors
    float V[3][3] = {{1.f, 0.f, 0.f}, {0.f, 1.f, 0.f}, {0.f, 0.f, 1.f}};
    auto rot = [&](int p, int q) {
        float apq = A[p][q];
        if (fabsf(apq) < 1e-30f) return;
        float theta = (A[q][q] - A[p][p]) / (2.0f * apq);
        float t = copysignf(1.0f, theta) / (fabsf(theta) + sqrtf(theta * theta + 1.0f));
        float c = 1.0f / sqrtf(t * t + 1.0f);
        float s = t * c;
#pragma unroll
        for (int k = 0; k < 3; ++k) {
            float akp = A[k][p], akq = A[k][q];
            A[k][p] = c * akp - s * akq;
            A[k][q] = s * akp + c * akq;
        }
#pragma unroll
        for (int k = 0; k < 3; ++k) {
            float apk = A[p][k], aqk = A[q][k];
            A[p][k] = c * apk - s * aqk;
            A[q][k] = s * apk + c * aqk;
        }
#pragma unroll
        for (int k = 0; k < 3; ++k) {
            float vkp = V[k][p], vkq = V[k][q];
            V[k][p] = c * vkp - s * vkq;
            V[k][q] = s * vkp + c * vkq;
        }
    };
    for (int sweep = 0; sweep < 8; ++sweep) {
        rot(0, 1);
        rot(0, 2);
        rot(1, 2);
    }

    // sort eigenpairs descending
    float lam[3] = {A[0][0], A[1][1], A[2][2]};
    int idx[3] = {0, 1, 2};
#pragma unroll
    for (int i = 0; i < 2; ++i)
#pragma unroll
        for (int j = i + 1; j < 3; ++j)
            if (lam[idx[j]] > lam[idx[i]]) { int tmp = idx[i]; idx[i] = idx[j]; idx[j] = tmp; }

    float v1[3], v2[3], v3[3];
#pragma unroll
    for (int i = 0; i < 3; ++i) {
        v1[i] = V[i][idx[0]];
        v2[i] = V[i][idx[1]];
        v3[i] = V[i][idx[2]];
    }

    // u1 = norm(H v1); u2 = GramSchmidt(H v2); u3 = u1 x u2  (det U = +1)
    float u1[3], u2[3], u3[3], hv[3];
    hv[0] = H[0][0]*v1[0] + H[0][1]*v1[1] + H[0][2]*v1[2];
    hv[1] = H[1][0]*v1[0] + H[1][1]*v1[1] + H[1][2]*v1[2];
    hv[2] = H[2][0]*v1[0] + H[2][1]*v1[1] + H[2][2]*v1[2];
    {
        float n = 1.0f / sqrtf(hv[0]*hv[0] + hv[1]*hv[1] + hv[2]*hv[2]);
        u1[0] = hv[0] * n; u1[1] = hv[1] * n; u1[2] = hv[2] * n;
    }
    hv[0] = H[0][0]*v2[0] + H[0][1]*v2[1] + H[0][2]*v2[2];
    hv[1] = H[1][0]*v2[0] + H[1][1]*v2[1] + H[1][2]*v2[2];
    hv[2] = H[2][0]*v2[0] + H[2][1]*v2[1] + H[2][2]*v2[2];
    {
        float d = u1[0]*hv[0] + u1[1]*hv[1] + u1[2]*hv[2];
        hv[0] -= d * u1[0]; hv[1] -= d * u1[1]; hv[2] -= d * u1[2];
        float n = 1.0f / sqrtf(hv[0]*hv[0] + hv[1]*hv[1] + hv[2]*hv[2]);
        u2[0] = hv[0] * n; u2[1] = hv[1] * n; u2[2] = hv[2] * n;
    }
    u3[0] = u1[1]*u2[2] - u1[2]*u2[1];
    u3[1] = u1[2]*u2[0] - u1[0]*u2[2];
    u3[2] = u1[0]*u2[1] - u1[1]*u2[0];

    // R = v1 u1^T + v2 u2^T + det(V) * v3 u3^T
    float cx = v1[1]*v2[2] - v1[2]*v2[1];
    float cy = v1[2]*v2[0] - v1[0]*v2[2];
    float cz = v1[0]*v2[1] - v1[1]*v2[0];
    float detV = cx * v3[0] + cy * v3[1] + cz * v3[2];
    float d3 = (detV < 0.f) ? -1.f : 1.f;

    float R[3][3];
#pragma unroll
    for (int i = 0; i < 3; ++i)
#pragma unroll
        for (int j = 0; j < 3; ++j)
            R[i][j] = v1[i]*u1[j] + v2[i]*u2[j] + d3 * v3[i]*u3[j];

    float tvec[3];
#pragma unroll
    for (int i = 0; i < 3; ++i)
        tvec[i] = mut[i] - (R[i][0]*mus[0] + R[i][1]*mus[1] + R[i][2]*mus[2]);

    float* Rout = out + (size_t)b * 9;
#pragma unroll
    for (int i = 0; i < 3; ++i)
#pragma unroll
        for (int j = 0; j < 3; ++j)
            Rout[i * 3 + j] = R[i][j];
    float* tout = out + (size_t)nbatch * 9 + (size_t)b * 3;
#pragma unroll
    for (int i = 0; i < 3; ++i) tout[i] = tvec[i];
}

extern "C" void kernel_launch(void* const* d_in, const int* in_sizes, int n_in,
                              void* d_out, int out_size, void* d_ws, size_t ws_size,
                              hipStream_t stream) {
    const float* src = (const float*)d_in[0];
    const float* tgt = (const float*)d_in[1];
    float* out = (float*)d_out;
    const int nbatch = in_sizes[0] / (NPTS * 3);
    const int nblocks = (nbatch + WAVES_PER_BLOCK - 1) / WAVES_PER_BLOCK;
    kabsch_kernel<<<nblocks, 256, 0, stream>>>(src, tgt, out, nbatch);
}

// Round 3
// 28.183 us; speedup vs baseline: 2.7528x; 2.3011x over previous
//
#include <hip/hip_runtime.h>
#include <math.h>

constexpr int NPTS = 1024;
constexpr int WPB = 4;   // waves per block, phase A

// ---------------- Phase A: per-batch 15-sum reduction (memory-bound) -------
__global__ __launch_bounds__(256) void reduce_kernel(
    const float* __restrict__ src, const float* __restrict__ tgt,
    float* __restrict__ ws, int nbatch)
{
    const int wave = threadIdx.x >> 6;
    const int lane = threadIdx.x & 63;
    const int b = blockIdx.x * WPB + wave;
    if (b >= nbatch) return;

    const size_t base = (size_t)b * (NPTS * 3);

    float acc[15];
#pragma unroll
    for (int i = 0; i < 15; ++i) acc[i] = 0.f;

    // Each lane: 4 groups of 4 points (12 contiguous floats = 3 float4s)
#pragma unroll
    for (int j = 0; j < 4; ++j) {
        const int g = j * 64 + lane;
        const float* sp = src + base + g * 12;
        const float* tp = tgt + base + g * 12;
        float4 sA = *(const float4*)(sp + 0);
        float4 sB = *(const float4*)(sp + 4);
        float4 sC = *(const float4*)(sp + 8);
        float4 tA = *(const float4*)(tp + 0);
        float4 tB = *(const float4*)(tp + 4);
        float4 tC = *(const float4*)(tp + 8);

        float sx[4] = {sA.x, sA.w, sB.z, sC.y};
        float sy[4] = {sA.y, sB.x, sB.w, sC.z};
        float sz[4] = {sA.z, sB.y, sC.x, sC.w};
        float tx[4] = {tA.x, tA.w, tB.z, tC.y};
        float ty[4] = {tA.y, tB.x, tB.w, tC.z};
        float tz[4] = {tA.z, tB.y, tC.x, tC.w};

#pragma unroll
        for (int k = 0; k < 4; ++k) {
            acc[0] += sx[k]; acc[1] += sy[k]; acc[2] += sz[k];
            acc[3] += tx[k]; acc[4] += ty[k]; acc[5] += tz[k];
            acc[6]  += sx[k] * tx[k]; acc[7]  += sx[k] * ty[k]; acc[8]  += sx[k] * tz[k];
            acc[9]  += sy[k] * tx[k]; acc[10] += sy[k] * ty[k]; acc[11] += sy[k] * tz[k];
            acc[12] += sz[k] * tx[k]; acc[13] += sz[k] * ty[k]; acc[14] += sz[k] * tz[k];
        }
    }

#pragma unroll
    for (int off = 32; off >= 1; off >>= 1) {
#pragma unroll
        for (int i = 0; i < 15; ++i)
            acc[i] += __shfl_down(acc[i], off, 64);
    }

    if (lane == 0) {
        float4* w = (float4*)(ws + (size_t)b * 16);
        w[0] = make_float4(acc[0],  acc[1],  acc[2],  acc[3]);
        w[1] = make_float4(acc[4],  acc[5],  acc[6],  acc[7]);
        w[2] = make_float4(acc[8],  acc[9],  acc[10], acc[11]);
        w[3] = make_float4(acc[12], acc[13], acc[14], 0.f);
    }
}

// ---------------- Phase B: one 3x3 SVD per LANE (VALU, fully lane-parallel) -
__global__ __launch_bounds__(256) void svd_kernel(
    const float* __restrict__ ws, float* __restrict__ out, int nbatch)
{
    const int b = blockIdx.x * 256 + threadIdx.x;
    if (b >= nbatch) return;

    const float4* w = (const float4*)(ws + (size_t)b * 16);
    float4 w0 = w[0], w1 = w[1], w2 = w[2], w3 = w[3];
    float r[15] = {w0.x, w0.y, w0.z, w0.w,
                   w1.x, w1.y, w1.z, w1.w,
                   w2.x, w2.y, w2.z, w2.w,
                   w3.x, w3.y, w3.z};

    const float invN = 1.0f / (float)NPTS;
    float mus[3] = {r[0] * invN, r[1] * invN, r[2] * invN};
    float mut[3] = {r[3] * invN, r[4] * invN, r[5] * invN};

    float H[3][3];
#pragma unroll
    for (int i = 0; i < 3; ++i)
#pragma unroll
        for (int j = 0; j < 3; ++j)
            H[i][j] = r[6 + i * 3 + j] - (float)NPTS * mus[i] * mut[j];

    // A = H^T H
    float A[3][3];
#pragma unroll
    for (int i = 0; i < 3; ++i)
#pragma unroll
        for (int j = 0; j < 3; ++j)
            A[i][j] = H[0][i] * H[0][j] + H[1][i] * H[1][j] + H[2][i] * H[2][j];

    float V[3][3] = {{1.f, 0.f, 0.f}, {0.f, 1.f, 0.f}, {0.f, 0.f, 1.f}};
    auto rot = [&](int p, int q) {
        float apq = A[p][q];
        float diff = A[q][q] - A[p][p];
        bool tiny = (fabsf(apq) < 1e-25f);
        float denom = tiny ? 1.0f : (2.0f * apq);
        float theta = diff / denom;
        float t = copysignf(1.0f, theta) / (fabsf(theta) + sqrtf(theta * theta + 1.0f));
        t = tiny ? 0.0f : t;
        float c = 1.0f / sqrtf(t * t + 1.0f);
        float s = t * c;
#pragma unroll
        for (int k = 0; k < 3; ++k) {
            float akp = A[k][p], akq = A[k][q];
            A[k][p] = c * akp - s * akq;
            A[k][q] = s * akp + c * akq;
        }
#pragma unroll
        for (int k = 0; k < 3; ++k) {
            float apk = A[p][k], aqk = A[q][k];
            A[p][k] = c * apk - s * aqk;
            A[q][k] = s * apk + c * aqk;
        }
#pragma unroll
        for (int k = 0; k < 3; ++k) {
            float vkp = V[k][p], vkq = V[k][q];
            V[k][p] = c * vkp - s * vkq;
            V[k][q] = s * vkp + c * vkq;
        }
    };
#pragma unroll
    for (int sweep = 0; sweep < 7; ++sweep) {
        rot(0, 1);
        rot(0, 2);
        rot(1, 2);
    }

    // branchless descending sort of eigenpairs
    float l0 = A[0][0], l1 = A[1][1], l2 = A[2][2];
    float e0[3] = {V[0][0], V[1][0], V[2][0]};
    float e1[3] = {V[0][1], V[1][1], V[2][1]};
    float e2[3] = {V[0][2], V[1][2], V[2][2]};
    auto cswap = [](float& la, float* va, float& lb, float* vb) {
        bool sw = lb > la;
        float tl = sw ? lb : la;
        lb = sw ? la : lb;
        la = tl;
#pragma unroll
        for (int k = 0; k < 3; ++k) {
            float tv = sw ? vb[k] : va[k];
            vb[k] = sw ? va[k] : vb[k];
            va[k] = tv;
        }
    };
    cswap(l0, e0, l1, e1);
    cswap(l0, e0, l2, e2);
    cswap(l1, e1, l2, e2);

    float *v1 = e0, *v2 = e1, *v3 = e2;

    // u1 = norm(H v1); u2 = GramSchmidt(H v2); u3 = u1 x u2
    float u1[3], u2[3], u3[3], hv[3];
    hv[0] = H[0][0]*v1[0] + H[0][1]*v1[1] + H[0][2]*v1[2];
    hv[1] = H[1][0]*v1[0] + H[1][1]*v1[1] + H[1][2]*v1[2];
    hv[2] = H[2][0]*v1[0] + H[2][1]*v1[1] + H[2][2]*v1[2];
    {
        float n = 1.0f / sqrtf(hv[0]*hv[0] + hv[1]*hv[1] + hv[2]*hv[2]);
        u1[0] = hv[0] * n; u1[1] = hv[1] * n; u1[2] = hv[2] * n;
    }
    hv[0] = H[0][0]*v2[0] + H[0][1]*v2[1] + H[0][2]*v2[2];
    hv[1] = H[1][0]*v2[0] + H[1][1]*v2[1] + H[1][2]*v2[2];
    hv[2] = H[2][0]*v2[0] + H[2][1]*v2[1] + H[2][2]*v2[2];
    {
        float d = u1[0]*hv[0] + u1[1]*hv[1] + u1[2]*hv[2];
        hv[0] -= d * u1[0]; hv[1] -= d * u1[1]; hv[2] -= d * u1[2];
        float n = 1.0f / sqrtf(hv[0]*hv[0] + hv[1]*hv[1] + hv[2]*hv[2]);
        u2[0] = hv[0] * n; u2[1] = hv[1] * n; u2[2] = hv[2] * n;
    }
    u3[0] = u1[1]*u2[2] - u1[2]*u2[1];
    u3[1] = u1[2]*u2[0] - u1[0]*u2[2];
    u3[2] = u1[0]*u2[1] - u1[1]*u2[0];

    // R = v1 u1^T + v2 u2^T + det(V) * v3 u3^T
    float cx = v1[1]*v2[2] - v1[2]*v2[1];
    float cy = v1[2]*v2[0] - v1[0]*v2[2];
    float cz = v1[0]*v2[1] - v1[1]*v2[0];
    float detV = cx * v3[0] + cy * v3[1] + cz * v3[2];
    float d3 = (detV < 0.f) ? -1.f : 1.f;

    float R[3][3];
#pragma unroll
    for (int i = 0; i < 3; ++i)
#pragma unroll
        for (int j = 0; j < 3; ++j)
            R[i][j] = v1[i]*u1[j] + v2[i]*u2[j] + d3 * v3[i]*u3[j];

    float tvec[3];
#pragma unroll
    for (int i = 0; i < 3; ++i)
        tvec[i] = mut[i] - (R[i][0]*mus[0] + R[i][1]*mus[1] + R[i][2]*mus[2]);

    float* Rout = out + (size_t)b * 9;
#pragma unroll
    for (int i = 0; i < 3; ++i)
#pragma unroll
        for (int j = 0; j < 3; ++j)
            Rout[i * 3 + j] = R[i][j];
    float* tout = out + (size_t)nbatch * 9 + (size_t)b * 3;
#pragma unroll
    for (int i = 0; i < 3; ++i) tout[i] = tvec[i];
}

extern "C" void kernel_launch(void* const* d_in, const int* in_sizes, int n_in,
                              void* d_out, int out_size, void* d_ws, size_t ws_size,
                              hipStream_t stream) {
    const float* src = (const float*)d_in[0];
    const float* tgt = (const float*)d_in[1];
    float* out = (float*)d_out;
    float* ws = (float*)d_ws;
    const int nbatch = in_sizes[0] / (NPTS * 3);

    const int nblocksA = (nbatch + WPB - 1) / WPB;
    reduce_kernel<<<nblocksA, 256, 0, stream>>>(src, tgt, ws, nbatch);

    const int nblocksB = (nbatch + 255) / 256;
    svd_kernel<<<nblocksB, 256, 0, stream>>>(ws, out, nbatch);
}

// Round 4
// 24.909 us; speedup vs baseline: 3.1146x; 1.1314x over previous
//
#include <hip/hip_runtime.h>
#include <math.h>

constexpr int NPTS = 1024;
constexpr int WPB = 4;   // waves per block, phase A

// ---------------- Phase A: per-batch 15-sum reduction (memory-bound) -------
__global__ __launch_bounds__(256) void reduce_kernel(
    const float* __restrict__ src, const float* __restrict__ tgt,
    float* __restrict__ ws, int nbatch)
{
    const int wave = threadIdx.x >> 6;
    const int lane = threadIdx.x & 63;
    const int b = blockIdx.x * WPB + wave;
    if (b >= nbatch) return;

    const size_t base = (size_t)b * (NPTS * 3);

    float acc[15];
#pragma unroll
    for (int i = 0; i < 15; ++i) acc[i] = 0.f;

    // Each lane: 4 groups of 4 points (12 contiguous floats = 3 float4s)
#pragma unroll
    for (int j = 0; j < 4; ++j) {
        const int g = j * 64 + lane;
        const float* sp = src + base + g * 12;
        const float* tp = tgt + base + g * 12;
        float4 sA = *(const float4*)(sp + 0);
        float4 sB = *(const float4*)(sp + 4);
        float4 sC = *(const float4*)(sp + 8);
        float4 tA = *(const float4*)(tp + 0);
        float4 tB = *(const float4*)(tp + 4);
        float4 tC = *(const float4*)(tp + 8);

        float sx[4] = {sA.x, sA.w, sB.z, sC.y};
        float sy[4] = {sA.y, sB.x, sB.w, sC.z};
        float sz[4] = {sA.z, sB.y, sC.x, sC.w};
        float tx[4] = {tA.x, tA.w, tB.z, tC.y};
        float ty[4] = {tA.y, tB.x, tB.w, tC.z};
        float tz[4] = {tA.z, tB.y, tC.x, tC.w};

#pragma unroll
        for (int k = 0; k < 4; ++k) {
            acc[0] += sx[k]; acc[1] += sy[k]; acc[2] += sz[k];
            acc[3] += tx[k]; acc[4] += ty[k]; acc[5] += tz[k];
            acc[6]  += sx[k] * tx[k]; acc[7]  += sx[k] * ty[k]; acc[8]  += sx[k] * tz[k];
            acc[9]  += sy[k] * tx[k]; acc[10] += sy[k] * ty[k]; acc[11] += sy[k] * tz[k];
            acc[12] += sz[k] * tx[k]; acc[13] += sz[k] * ty[k]; acc[14] += sz[k] * tz[k];
        }
    }

#pragma unroll
    for (int off = 32; off >= 1; off >>= 1) {
#pragma unroll
        for (int i = 0; i < 15; ++i)
            acc[i] += __shfl_down(acc[i], off, 64);
    }

    if (lane == 0) {
        float4* w = (float4*)(ws + (size_t)b * 16);
        w[0] = make_float4(acc[0],  acc[1],  acc[2],  acc[3]);
        w[1] = make_float4(acc[4],  acc[5],  acc[6],  acc[7]);
        w[2] = make_float4(acc[8],  acc[9],  acc[10], acc[11]);
        w[3] = make_float4(acc[12], acc[13], acc[14], 0.f);
    }
}

// fast HW approximations (v_rcp_f32 / v_rsq_f32 / v_sqrt_f32, ~1ulp)
__device__ __forceinline__ float frcp(float x)  { return __builtin_amdgcn_rcpf(x); }
__device__ __forceinline__ float frsq(float x)  { return __builtin_amdgcn_rsqf(x); }
__device__ __forceinline__ float fsqrt(float x) { return __builtin_amdgcn_sqrtf(x); }

// ---------------- Phase B: one 3x3 SVD per LANE (latency-bound chain) ------
__global__ __launch_bounds__(256) void svd_kernel(
    const float* __restrict__ ws, float* __restrict__ out, int nbatch)
{
    const int b = blockIdx.x * 256 + threadIdx.x;
    if (b >= nbatch) return;

    const float4* w = (const float4*)(ws + (size_t)b * 16);
    float4 w0 = w[0], w1 = w[1], w2 = w[2], w3 = w[3];
    float r[15] = {w0.x, w0.y, w0.z, w0.w,
                   w1.x, w1.y, w1.z, w1.w,
                   w2.x, w2.y, w2.z, w2.w,
                   w3.x, w3.y, w3.z};

    const float invN = 1.0f / (float)NPTS;
    float mus[3] = {r[0] * invN, r[1] * invN, r[2] * invN};
    float mut[3] = {r[3] * invN, r[4] * invN, r[5] * invN};

    float H[3][3];
#pragma unroll
    for (int i = 0; i < 3; ++i)
#pragma unroll
        for (int j = 0; j < 3; ++j)
            H[i][j] = r[6 + i * 3 + j] - (float)NPTS * mus[i] * mut[j];

    // A = H^T H (symmetric PSD)
    float A[3][3];
#pragma unroll
    for (int i = 0; i < 3; ++i)
#pragma unroll
        for (int j = 0; j < 3; ++j)
            A[i][j] = H[0][i] * H[0][j] + H[1][i] * H[1][j] + H[2][i] * H[2][j];

    // cyclic Jacobi with HW-fast rcp/rsq/sqrt (short dependent chain)
    float V[3][3] = {{1.f, 0.f, 0.f}, {0.f, 1.f, 0.f}, {0.f, 0.f, 1.f}};
    auto rot = [&](int p, int q) {
        float apq = A[p][q];
        float diff = A[q][q] - A[p][p];
        float theta = diff * frcp(2.0f * apq);
        float t = copysignf(frcp(fabsf(theta) + fsqrt(fmaf(theta, theta, 1.0f))), theta);
        // apq==0 -> theta inf/nan -> guard to identity rotation
        t = (fabsf(apq) < 1e-20f) ? 0.0f : t;
        float c = frsq(fmaf(t, t, 1.0f));
        float s = t * c;
#pragma unroll
        for (int k = 0; k < 3; ++k) {
            float akp = A[k][p], akq = A[k][q];
            A[k][p] = c * akp - s * akq;
            A[k][q] = s * akp + c * akq;
        }
#pragma unroll
        for (int k = 0; k < 3; ++k) {
            float apk = A[p][k], aqk = A[q][k];
            A[p][k] = c * apk - s * aqk;
            A[q][k] = s * apk + c * aqk;
        }
#pragma unroll
        for (int k = 0; k < 3; ++k) {
            float vkp = V[k][p], vkq = V[k][q];
            V[k][p] = c * vkp - s * vkq;
            V[k][q] = s * vkp + c * vkq;
        }
    };
#pragma unroll
    for (int sweep = 0; sweep < 5; ++sweep) {
        rot(0, 1);
        rot(0, 2);
        rot(1, 2);
    }

    // branchless descending sort of eigenpairs
    float l0 = A[0][0], l1 = A[1][1], l2 = A[2][2];
    float e0[3] = {V[0][0], V[1][0], V[2][0]};
    float e1[3] = {V[0][1], V[1][1], V[2][1]};
    float e2[3] = {V[0][2], V[1][2], V[2][2]};
    auto cswap = [](float& la, float* va, float& lb, float* vb) {
        bool sw = lb > la;
        float tl = sw ? lb : la;
        lb = sw ? la : lb;
        la = tl;
#pragma unroll
        for (int k = 0; k < 3; ++k) {
            float tv = sw ? vb[k] : va[k];
            vb[k] = sw ? va[k] : vb[k];
            va[k] = tv;
        }
    };
    cswap(l0, e0, l1, e1);
    cswap(l0, e0, l2, e2);
    cswap(l1, e1, l2, e2);

    float *v1 = e0, *v2 = e1, *v3 = e2;

    // u1 = norm(H v1); u2 = GramSchmidt(H v2); u3 = u1 x u2  (det U = +1)
    float u1[3], u2[3], u3[3], hv[3];
    hv[0] = H[0][0]*v1[0] + H[0][1]*v1[1] + H[0][2]*v1[2];
    hv[1] = H[1][0]*v1[0] + H[1][1]*v1[1] + H[1][2]*v1[2];
    hv[2] = H[2][0]*v1[0] + H[2][1]*v1[1] + H[2][2]*v1[2];
    {
        float n = frsq(fmaf(hv[0], hv[0], fmaf(hv[1], hv[1], hv[2]*hv[2])) + 1e-30f);
        u1[0] = hv[0] * n; u1[1] = hv[1] * n; u1[2] = hv[2] * n;
    }
    hv[0] = H[0][0]*v2[0] + H[0][1]*v2[1] + H[0][2]*v2[2];
    hv[1] = H[1][0]*v2[0] + H[1][1]*v2[1] + H[1][2]*v2[2];
    hv[2] = H[2][0]*v2[0] + H[2][1]*v2[1] + H[2][2]*v2[2];
    {
        float d = u1[0]*hv[0] + u1[1]*hv[1] + u1[2]*hv[2];
        hv[0] -= d * u1[0]; hv[1] -= d * u1[1]; hv[2] -= d * u1[2];
        float n = frsq(fmaf(hv[0], hv[0], fmaf(hv[1], hv[1], hv[2]*hv[2])) + 1e-30f);
        u2[0] = hv[0] * n; u2[1] = hv[1] * n; u2[2] = hv[2] * n;
    }
    u3[0] = u1[1]*u2[2] - u1[2]*u2[1];
    u3[1] = u1[2]*u2[0] - u1[0]*u2[2];
    u3[2] = u1[0]*u2[1] - u1[1]*u2[0];

    // R = v1 u1^T + v2 u2^T + det(V) * v3 u3^T
    float cx = v1[1]*v2[2] - v1[2]*v2[1];
    float cy = v1[2]*v2[0] - v1[0]*v2[2];
    float cz = v1[0]*v2[1] - v1[1]*v2[0];
    float detV = cx * v3[0] + cy * v3[1] + cz * v3[2];
    float d3 = (detV < 0.f) ? -1.f : 1.f;

    float R[3][3];
#pragma unroll
    for (int i = 0; i < 3; ++i)
#pragma unroll
        for (int j = 0; j < 3; ++j)
            R[i][j] = v1[i]*u1[j] + v2[i]*u2[j] + d3 * v3[i]*u3[j];

    float tvec[3];
#pragma unroll
    for (int i = 0; i < 3; ++i)
        tvec[i] = mut[i] - (R[i][0]*mus[0] + R[i][1]*mus[1] + R[i][2]*mus[2]);

    float* Rout = out + (size_t)b * 9;
#pragma unroll
    for (int i = 0; i < 3; ++i)
#pragma unroll
        for (int j = 0; j < 3; ++j)
            Rout[i * 3 + j] = R[i][j];
    float* tout = out + (size_t)nbatch * 9 + (size_t)b * 3;
#pragma unroll
    for (int i = 0; i < 3; ++i) tout[i] = tvec[i];
}

extern "C" void kernel_launch(void* const* d_in, const int* in_sizes, int n_in,
                              void* d_out, int out_size, void* d_ws, size_t ws_size,
                              hipStream_t stream) {
    const float* src = (const float*)d_in[0];
    const float* tgt = (const float*)d_in[1];
    float* out = (float*)d_out;
    float* ws = (float*)d_ws;
    const int nbatch = in_sizes[0] / (NPTS * 3);

    const int nblocksA = (nbatch + WPB - 1) / WPB;
    reduce_kernel<<<nblocksA, 256, 0, stream>>>(src, tgt, ws, nbatch);

    const int nblocksB = (nbatch + 255) / 256;
    svd_kernel<<<nblocksB, 256, 0, stream>>>(ws, out, nbatch);
}